// Round 1
// baseline (3802.588 us; speedup 1.0000x reference)
//
#include <hip/hip_runtime.h>

#define SEQ 64
#define BAT 256
#define NT 32
#define EMB 256
#define HID 256
#define G3 768   // 3*HID

typedef __bf16 bf16x8 __attribute__((ext_vector_type(8)));
typedef float f32x4 __attribute__((ext_vector_type(4)));

__device__ __forceinline__ float sigm(float x) {
    x = fminf(fmaxf(x, -30.f), 30.f);
    return 1.f / (1.f + __expf(-x));
}
__device__ __forceinline__ float tanhr(float x) {
    x = fminf(fmaxf(x, -15.f), 15.f);
    float e = __expf(2.f * x);
    return (e - 1.f) / (e + 1.f);
}

// ---------------- K1: precompute G = emb @ W_ih.T + b_ih ; convert W_hh/W_lin to bf16 ----
__global__ void k_pre(const float* __restrict__ emb, const float* __restrict__ W_ih,
                      const float* __restrict__ b_ih, const float* __restrict__ W_hh,
                      const float* __restrict__ W_lin,
                      float* __restrict__ G, __bf16* __restrict__ Wbhh, __bf16* __restrict__ Wblin)
{
    const int tid = threadIdx.x;
    const int blk = blockIdx.x;
    if (blk < 33) {
        __shared__ float es[EMB];
        es[tid] = emb[blk * EMB + tid];
        __syncthreads();
        const float4* e4 = (const float4*)es;
        #pragma unroll
        for (int g = 0; g < 3; ++g) {
            int c = g * HID + tid;
            const float4* w4 = (const float4*)(W_ih + c * EMB);
            float acc = b_ih[c];
            #pragma unroll 8
            for (int i = 0; i < EMB / 4; ++i) {
                float4 a = e4[i], w = w4[i];
                acc += a.x * w.x + a.y * w.y + a.z * w.z + a.w * w.w;
            }
            G[blk * G3 + c] = acc;
        }
    } else {
        long base = (long)(blk - 33) * 2048 + (long)tid * 8;
        #pragma unroll
        for (int u = 0; u < 8; ++u) {
            long i = base + u;
            if (i < (long)G3 * EMB) Wbhh[i] = (__bf16)W_hh[i];
            else {
                long j = i - (long)G3 * EMB;
                if (j < NT * HID) Wblin[j] = (__bf16)W_lin[j];
            }
        }
    }
}

// ---------------- K2: h1 = gru(emb[32], 0), trans0 = h1 @ W_lin.T + b_lin (exact fp32) ----
__global__ void k_init(const float* __restrict__ G, const float* __restrict__ b_hh,
                       const float* __restrict__ W_lin, const float* __restrict__ b_lin,
                       float* __restrict__ h1, float* __restrict__ tr0)
{
    __shared__ float hs[HID];
    int j = threadIdx.x;
    float gr = G[32 * G3 + j], gz = G[32 * G3 + HID + j], gn = G[32 * G3 + 2 * HID + j];
    float r = sigm(gr + b_hh[j]);
    float z = sigm(gz + b_hh[HID + j]);
    float n = tanhr(gn + r * b_hh[2 * HID + j]);
    float h = (1.f - z) * n;   // h0 = 0
    h1[j] = h; hs[j] = h;
    __syncthreads();
    if (j < NT) {
        const float4* w4 = (const float4*)(W_lin + j * HID);
        const float4* h4 = (const float4*)hs;
        float acc = b_lin[j];
        #pragma unroll 8
        for (int i = 0; i < HID / 4; ++i) {
            float4 a = h4[i], w = w4[i];
            acc += a.x * w.x + a.y * w.y + a.z * w.z + a.w * w.w;
        }
        tr0[j] = acc;
    }
}

// ---------------- K3: one workgroup per batch element; full 63-step recurrence ----------
// LDS strides chosen for bank-conflict freedom: hn 257 (fp32), hb 264 (bf16, 16B-aligned
// rows for ds_read_b128 A-frags), gi 776 (bf16), srt/tr 33.
__global__ __launch_bounds__(256, 1) void k_main(
    const float* __restrict__ em, const int* __restrict__ tags, const float* __restrict__ mask,
    const float* __restrict__ G, const float* __restrict__ h1w, const float* __restrict__ tr0w,
    const __bf16* __restrict__ Wbhh, const __bf16* __restrict__ Wblin,
    const float* __restrict__ bhhg, const float* __restrict__ bling,
    float* __restrict__ out)
{
    __shared__ float hn[2][33 * 257];                       // fp32 hidden state ping-pong (rows 0..31 beams, 32 path)
    __shared__ __attribute__((aligned(16))) __bf16 hb[48 * 264];   // bf16 A-matrix (rows 33..47 zero)
    __shared__ __attribute__((aligned(16))) __bf16 gi[33 * 776];   // staged G rows per beam/path
    __shared__ float trs[33 * 33];
    __shared__ float srtv[32 * 33];
    __shared__ unsigned short srti[32 * 33];
    __shared__ float bhh[768];
    __shared__ float blin[NT];
    __shared__ float em0s[NT];
    __shared__ float base[NT];
    __shared__ float scores[NT];
    __shared__ int btag[NT];
    __shared__ int par[NT];
    __shared__ float s_ps;

    const int tid = threadIdx.x;
    const int b = blockIdx.x;
    const int w = tid >> 6;
    const int lane = tid & 63;
    const int q = lane >> 4;
    const int l15 = lane & 15;

    // ---- stage invariants ----
    bhh[tid] = bhhg[tid];
    bhh[256 + tid] = bhhg[256 + tid];
    bhh[512 + tid] = bhhg[512 + tid];
    if (tid < NT) { blin[tid] = bling[tid]; em0s[tid] = em[b * NT + tid]; }
    {
        float h1v = h1w[tid];
        for (int k = 0; k < 33; ++k) hn[0][k * 257 + tid] = h1v;
    }
    for (int i = tid; i < 15 * 264; i += 256) hb[33 * 264 + i] = (__bf16)0.f;
    if (tid < NT) par[tid] = tid;
    __syncthreads();

    // ---- initial top_k of s_init = (trans0 + em0) * mask0  (rank sort, ties -> lower idx) ----
    if (tid < NT) {
        float m0 = mask[b];
        float v = (tr0w[tid] + em0s[tid]) * m0;
        int cnt = 0;
        for (int jj = 0; jj < NT; ++jj) {
            float vj = __shfl(v, jj, 32);
            cnt += (vj > v) || (vj == v && jj < tid);
        }
        scores[cnt] = v; btag[cnt] = tid;
    }
    if (tid == 64) {
        int t0 = tags[b];
        s_ps = (tr0w[t0] + em0s[t0]) * mask[b];
    }
    __syncthreads();

    for (int t = 1; t < SEQ; ++t) {
        const int cur = (t - 1) & 1, nxt = t & 1;

        // (a) stage gi rows (bf16): beams use btag[], path row uses tags[t-1][b]
        {
            int pt = tags[(t - 1) * BAT + b];
            for (int k = 0; k < 33; ++k) {
                int e = (k < NT) ? btag[k] : pt;
                const float* gr = G + e * G3;
                gi[k * 776 + tid]       = (__bf16)gr[tid];
                gi[k * 776 + 256 + tid] = (__bf16)gr[256 + tid];
                gi[k * 776 + 512 + tid] = (__bf16)gr[512 + tid];
            }
        }
        // (b) build bf16 A-matrix from (parent-permuted) fp32 state
        for (int k = 0; k < 33; ++k) {
            int src = (k < NT) ? par[k] : 32;
            hb[k * 264 + tid] = (__bf16)hn[cur][src * 257 + tid];
        }
        __syncthreads();

        // (c) gh = hidden @ W_hh.T  (48x768x256 bf16 MFMA; wave w owns cols [64w,64w+64) per gate)
        f32x4 acc[3][3][4];
        #pragma unroll
        for (int mt = 0; mt < 3; ++mt)
            #pragma unroll
            for (int g = 0; g < 3; ++g)
                #pragma unroll
                for (int c4 = 0; c4 < 4; ++c4) {
                    f32x4 z = {0.f, 0.f, 0.f, 0.f};
                    acc[mt][g][c4] = z;
                }
        #pragma unroll
        for (int kt = 0; kt < 8; ++kt) {
            int kk = kt * 32 + q * 8;
            bf16x8 af[3];
            #pragma unroll
            for (int mt = 0; mt < 3; ++mt)
                af[mt] = *(const bf16x8*)&hb[(mt * 16 + l15) * 264 + kk];
            #pragma unroll
            for (int g = 0; g < 3; ++g)
                #pragma unroll
                for (int c4 = 0; c4 < 4; ++c4) {
                    int n = g * 256 + w * 64 + c4 * 16 + l15;
                    bf16x8 bfv = *(const bf16x8*)&Wbhh[n * 256 + kk];
                    #pragma unroll
                    for (int mt = 0; mt < 3; ++mt)
                        acc[mt][g][c4] = __builtin_amdgcn_mfma_f32_16x16x32_bf16(
                            af[mt], bfv, acc[mt][g][c4], 0, 0, 0);
                }
        }
        // (d1) GRU elementwise straight from accumulators (C-frag: col=lane&15, row=q*4+r)
        #pragma unroll
        for (int mt = 0; mt < 3; ++mt)
            #pragma unroll
            for (int c4 = 0; c4 < 4; ++c4) {
                int j = w * 64 + c4 * 16 + l15;
                float br_ = bhh[j], bz_ = bhh[256 + j], bn_ = bhh[512 + j];
                #pragma unroll
                for (int r = 0; r < 4; ++r) {
                    int row = mt * 16 + q * 4 + r;
                    if (row > 32) continue;
                    float gir = (float)gi[row * 776 + j];
                    float giz = (float)gi[row * 776 + 256 + j];
                    float gin = (float)gi[row * 776 + 512 + j];
                    float rr = sigm(gir + acc[mt][0][c4][r] + br_);
                    float zz = sigm(giz + acc[mt][1][c4][r] + bz_);
                    float nn = tanhr(gin + rr * (acc[mt][2][c4][r] + bn_));
                    int src = (row < NT) ? par[row] : 32;
                    float hold = hn[cur][src * 257 + j];
                    hn[nxt][row * 257 + j] = (1.f - zz) * nn + zz * hold;
                }
            }
        __syncthreads();
        // (d2) refresh bf16 A-matrix with hnew for the tr matmul
        for (int k = 0; k < 33; ++k)
            hb[k * 264 + tid] = (__bf16)hn[nxt][k * 257 + tid];
        __syncthreads();

        // (e) tr = hnew @ W_lin.T + b_lin  (waves 0..2, mt = w)
        if (w < 3) {
            f32x4 a2[2];
            { f32x4 z = {0.f, 0.f, 0.f, 0.f}; a2[0] = z; a2[1] = z; }
            #pragma unroll
            for (int kt = 0; kt < 8; ++kt) {
                int kk = kt * 32 + q * 8;
                bf16x8 af = *(const bf16x8*)&hb[(w * 16 + l15) * 264 + kk];
                #pragma unroll
                for (int nt = 0; nt < 2; ++nt) {
                    bf16x8 bfv = *(const bf16x8*)&Wblin[(nt * 16 + l15) * 256 + kk];
                    a2[nt] = __builtin_amdgcn_mfma_f32_16x16x32_bf16(af, bfv, a2[nt], 0, 0, 0);
                }
            }
            #pragma unroll
            for (int nt = 0; nt < 2; ++nt)
                #pragma unroll
                for (int r = 0; r < 4; ++r) {
                    int row = w * 16 + q * 4 + r;
                    int col = nt * 16 + l15;
                    if (row <= 32) trs[row * 33 + col] = a2[nt][r] + blin[col];
                }
        }
        __syncthreads();

        // (f) path score (faithful: em0 gathered every step) + (g) quirk base
        float m_t = mask[t * BAT + b];
        if (tid == 0) {
            int ct = tags[t * BAT + b];
            s_ps += (trs[32 * 33 + ct] + em0s[ct]) * m_t;
        }
        if (tid < NT) base[tid] = scores[btag[tid]];
        __syncthreads();

        // (h) per-beam-row rank sort of 32 candidates (8 groups x 4 rows)
        {
            int proc = tid >> 5, l32 = tid & 31;
            float emv = em[(t * BAT + b) * NT + l32];
            for (int i = 0; i < 4; ++i) {
                int k = proc * 4 + i;
                float v = base[k] + (trs[k * 33 + l32] + emv) * m_t;
                int cnt = 0;
                for (int jj = 0; jj < 32; ++jj) {
                    float vj = __shfl(v, jj, 32);
                    cnt += (vj > v) || (vj == v && jj < l32);
                }
                srtv[k * 33 + cnt] = v;
                srti[k * 33 + cnt] = (unsigned short)(k * 32 + l32);
            }
        }
        __syncthreads();

        // (i) 32-way merge of sorted rows -> global top-32 in exact lax.top_k order
        if (tid < NT) {
            int r = tid, p = 0;
            float hv = srtv[r * 33];
            for (int i = 0; i < 32; ++i) {
                float bv = hv; int brr = r;
                #pragma unroll
                for (int off = 16; off >= 1; off >>= 1) {
                    float ov = __shfl_xor(bv, off, 32);
                    int orr = __shfl_xor(brr, off, 32);
                    if (ov > bv || (ov == bv && orr < brr)) { bv = ov; brr = orr; }
                }
                if (r == brr) {
                    scores[i] = bv;
                    int idx = srti[r * 33 + p];
                    btag[i] = idx & 31;
                    par[i] = idx >> 5;
                    ++p;
                    hv = (p < 32) ? srtv[r * 33 + p] : -3.4e38f;
                }
            }
        }
        __syncthreads();
    }

    // ---- epilogue: logsumexp over sorted scores; accumulate (ps - logz) ----
    if (tid < NT) {
        float mx = scores[0];
        float ex = __expf(scores[tid] - mx);
        #pragma unroll
        for (int off = 16; off >= 1; off >>= 1) ex += __shfl_xor(ex, off, 32);
        if (tid == 0) {
            float logz = mx + logf(ex);
            atomicAdd(out, s_ps - logz);
        }
    }
}

extern "C" void kernel_launch(void* const* d_in, const int* in_sizes, int n_in,
                              void* d_out, int out_size, void* d_ws, size_t ws_size,
                              hipStream_t stream) {
    const float* emissions = (const float*)d_in[0];
    const int*   tags      = (const int*)d_in[1];
    const float* mask      = (const float*)d_in[2];
    const float* embedding = (const float*)d_in[3];
    const float* W_ih      = (const float*)d_in[4];
    const float* W_hh      = (const float*)d_in[5];
    const float* b_ih      = (const float*)d_in[6];
    const float* b_hh      = (const float*)d_in[7];
    const float* W_lin     = (const float*)d_in[8];
    const float* b_lin     = (const float*)d_in[9];
    float* out = (float*)d_out;

    char* ws = (char*)d_ws;
    float*  G     = (float*)ws;              // 33*768*4   = 101376 B
    float*  h1    = (float*)(ws + 101376);   // 256*4      = 1024 B
    float*  tr0   = (float*)(ws + 102400);   // 32*4       = 128 B
    __bf16* Wbhh  = (__bf16*)(ws + 102528);  // 768*256*2  = 393216 B
    __bf16* Wblin = (__bf16*)(ws + 495744);  // 32*256*2   = 16384 B  (end: 512128 B)

    hipMemsetAsync(d_out, 0, sizeof(float) * out_size, stream);
    k_pre<<<133, 256, 0, stream>>>(embedding, W_ih, b_ih, W_hh, W_lin, G, Wbhh, Wblin);
    k_init<<<1, 256, 0, stream>>>(G, b_hh, W_lin, b_lin, h1, tr0);
    k_main<<<BAT, 256, 0, stream>>>(emissions, tags, mask, G, h1, tr0,
                                    Wbhh, Wblin, b_hh, b_lin, out);
}

// Round 2
// 2219.641 us; speedup vs baseline: 1.7132x; 1.7132x over previous
//
#include <hip/hip_runtime.h>

#define SEQ 64
#define BAT 256
#define NT 32
#define EMB 256
#define HID 256
#define G3 768   // 3*HID

typedef __bf16 bf16x8 __attribute__((ext_vector_type(8)));
typedef float f32x4 __attribute__((ext_vector_type(4)));

__device__ __forceinline__ float sigm(float x) {
    x = fminf(fmaxf(x, -30.f), 30.f);
    return 1.f / (1.f + __expf(-x));
}
__device__ __forceinline__ float tanhr(float x) {
    x = fminf(fmaxf(x, -15.f), 15.f);
    float e = __expf(2.f * x);
    return (e - 1.f) / (e + 1.f);
}

// ---------------- K1: G = emb @ W_ih.T + b_ih ; pack W_hh/W_lin into MFMA-frag order ----
// Packed layout: chunk index ((coltile*8 + kt)*64 + lane), each chunk = 8 bf16 =
// W[coltile*16 + (lane&15)][kt*32 + (lane>>4)*8 + 0..7]  -> B-frag loads are 16B/lane coalesced.
__global__ void k_pre(const float* __restrict__ emb, const float* __restrict__ W_ih,
                      const float* __restrict__ b_ih, const float* __restrict__ W_hh,
                      const float* __restrict__ W_lin,
                      float* __restrict__ G, __bf16* __restrict__ Wpk, __bf16* __restrict__ Wlpk)
{
    const int tid = threadIdx.x;
    const int blk = blockIdx.x;
    if (blk < 33) {
        __shared__ float es[EMB];
        es[tid] = emb[blk * EMB + tid];
        __syncthreads();
        const float4* e4 = (const float4*)es;
        #pragma unroll
        for (int g = 0; g < 3; ++g) {
            int c = g * HID + tid;
            const float4* w4 = (const float4*)(W_ih + c * EMB);
            float acc = b_ih[c];
            #pragma unroll 8
            for (int i = 0; i < EMB / 4; ++i) {
                float4 a = e4[i], w = w4[i];
                acc += a.x * w.x + a.y * w.y + a.z * w.z + a.w * w.w;
            }
            G[blk * G3 + c] = acc;
        }
    } else {
        int idx = (blk - 33) * 256 + tid;   // [0, 25600)
        if (idx < 24576) {                  // W_hh: 48 col-tiles * 8 kt * 64 lanes
            int c    = idx >> 9;
            int rem  = idx & 511;
            int kt   = rem >> 6;
            int lane = rem & 63;
            int row  = c * 16 + (lane & 15);
            int col  = kt * 32 + (lane >> 4) * 8;
            const float* src = W_hh + row * 256 + col;
            bf16x8 v;
            #pragma unroll
            for (int j = 0; j < 8; ++j) v[j] = (__bf16)src[j];
            *(bf16x8*)(Wpk + idx * 8) = v;
        } else {                            // W_lin: 2 col-tiles * 8 kt * 64 lanes
            int i2   = idx - 24576;
            int nt   = i2 >> 9;
            int rem  = i2 & 511;
            int kt   = rem >> 6;
            int lane = rem & 63;
            int row  = nt * 16 + (lane & 15);
            int col  = kt * 32 + (lane >> 4) * 8;
            const float* src = W_lin + row * 256 + col;
            bf16x8 v;
            #pragma unroll
            for (int j = 0; j < 8; ++j) v[j] = (__bf16)src[j];
            *(bf16x8*)(Wlpk + i2 * 8) = v;
        }
    }
}

// ---------------- K2: h1 = gru(emb[32], 0), trans0 = h1 @ W_lin.T + b_lin (exact fp32) ----
__global__ void k_init(const float* __restrict__ G, const float* __restrict__ b_hh,
                       const float* __restrict__ W_lin, const float* __restrict__ b_lin,
                       float* __restrict__ h1, float* __restrict__ tr0)
{
    __shared__ float hs[HID];
    int j = threadIdx.x;
    float gr = G[32 * G3 + j], gz = G[32 * G3 + HID + j], gn = G[32 * G3 + 2 * HID + j];
    float r = sigm(gr + b_hh[j]);
    float z = sigm(gz + b_hh[HID + j]);
    float n = tanhr(gn + r * b_hh[2 * HID + j]);
    float h = (1.f - z) * n;   // h0 = 0
    h1[j] = h; hs[j] = h;
    __syncthreads();
    if (j < NT) {
        const float4* w4 = (const float4*)(W_lin + j * HID);
        const float4* h4 = (const float4*)hs;
        float acc = b_lin[j];
        #pragma unroll 8
        for (int i = 0; i < HID / 4; ++i) {
            float4 a = h4[i], w = w4[i];
            acc += a.x * w.x + a.y * w.y + a.z * w.z + a.w * w.w;
        }
        tr0[j] = acc;
    }
}

// ---------------- K3: one 1024-thread workgroup (16 waves) per batch element ----------
// Wave w owns within-gate column slice j = w*16 + l15 across ALL 3 gates -> GRU
// elementwise runs straight out of the 9 accumulators, G read directly from global.
__global__ __launch_bounds__(1024, 4) void k_main(
    const float* __restrict__ em, const int* __restrict__ tags, const float* __restrict__ mask,
    const float* __restrict__ G, const float* __restrict__ h1w, const float* __restrict__ tr0w,
    const __bf16* __restrict__ Wpk, const __bf16* __restrict__ Wlpk,
    const float* __restrict__ bhhg, const float* __restrict__ bling,
    float* __restrict__ out)
{
    __shared__ float hn[2][33 * 260];                            // fp32 state ping-pong (row 32 = path)
    __shared__ __attribute__((aligned(16))) __bf16 hb[48 * 264]; // bf16 A-matrix (rows 33..47 zero)
    __shared__ __attribute__((aligned(16))) __bf16 wlin[8192];   // packed W_lin frags
    __shared__ float trs[33 * 33];
    __shared__ float srtv[32 * 33];
    __shared__ unsigned short srti[32 * 33];
    __shared__ float bhh[768];
    __shared__ float em_s[SEQ * NT];
    __shared__ float mask_s[SEQ];
    __shared__ int tags_s[SEQ];
    __shared__ float scores[NT], blin_s[NT];
    __shared__ int btag[NT], par[NT];
    __shared__ float s_ps;

    const int tid = threadIdx.x;
    const int b = blockIdx.x;
    const int w = tid >> 6;
    const int lane = tid & 63;
    const int q = lane >> 4;
    const int l15 = lane & 15;

    // ---- prologue staging ----
    if (tid < 768) bhh[tid] = bhhg[tid];
    else if (tid < 832) mask_s[tid - 768] = mask[(tid - 768) * BAT + b];
    else if (tid < 896) tags_s[tid - 832] = tags[(tid - 832) * BAT + b];
    else if (tid < 928) { int i = tid - 896; blin_s[i] = bling[i]; par[i] = i; }
    ((bf16x8*)wlin)[tid] = ((const bf16x8*)Wlpk)[tid];
    for (int idx = tid; idx < SEQ * NT; idx += 1024)
        em_s[idx] = em[((idx >> 5) * BAT + b) * NT + (idx & 31)];
    for (int idx = tid; idx < 33 * 256; idx += 1024)
        hn[0][(idx >> 8) * 260 + (idx & 255)] = h1w[idx & 255];
    for (int idx = tid; idx < 15 * 264; idx += 1024)
        hb[33 * 264 + idx] = (__bf16)0.f;
    __syncthreads();

    // ---- initial top_k of s_init = (trans0 + em0) * mask0 (rank sort, ties -> lower idx) ----
    if (tid < 32) {
        float m0 = mask_s[0];
        float v = (tr0w[tid] + em_s[tid]) * m0;
        int cnt = 0;
        for (int jj = 0; jj < 32; ++jj) {
            float vj = __shfl(v, jj, 32);
            cnt += (vj > v) || (vj == v && jj < tid);
        }
        scores[cnt] = v; btag[cnt] = tid;
    }
    if (tid == 64) {
        int t0 = tags_s[0];
        s_ps = (tr0w[t0] + em_s[t0]) * mask_s[0];
    }
    __syncthreads();

    for (int t = 1; t < SEQ; ++t) {
        const int cur = (t - 1) & 1, nxt = t & 1;

        // (b) hb <- parent-permuted bf16 state
        for (int idx = tid; idx < 33 * 64; idx += 1024) {
            int k = idx >> 6, jq = (idx & 63) * 4;
            int src = (k < 32) ? par[k] : 32;
            const float* hp = &hn[cur][src * 260 + jq];
            __bf16* dp = &hb[k * 264 + jq];
            dp[0] = (__bf16)hp[0]; dp[1] = (__bf16)hp[1];
            dp[2] = (__bf16)hp[2]; dp[3] = (__bf16)hp[3];
        }
        __syncthreads();

        // (c) gh = hidden @ W_hh.T  (48x768x256; wave w -> cols w*16..w*16+15 of each gate)
        f32x4 acc[3][3];
        #pragma unroll
        for (int mt = 0; mt < 3; ++mt)
            #pragma unroll
            for (int g = 0; g < 3; ++g) {
                f32x4 z = {0.f, 0.f, 0.f, 0.f};
                acc[mt][g] = z;
            }
        #pragma unroll
        for (int kt = 0; kt < 8; ++kt) {
            const int kk = kt * 32 + q * 8;
            bf16x8 af0 = *(const bf16x8*)&hb[l15 * 264 + kk];
            bf16x8 af1 = *(const bf16x8*)&hb[(16 + l15) * 264 + kk];
            bf16x8 af2 = *(const bf16x8*)&hb[(32 + l15) * 264 + kk];
            #pragma unroll
            for (int g = 0; g < 3; ++g) {
                bf16x8 bv = *(const bf16x8*)(Wpk + ((((g * 16 + w) * 8 + kt) * 64 + lane) * 8));
                acc[0][g] = __builtin_amdgcn_mfma_f32_16x16x32_bf16(af0, bv, acc[0][g], 0, 0, 0);
                acc[1][g] = __builtin_amdgcn_mfma_f32_16x16x32_bf16(af1, bv, acc[1][g], 0, 0, 0);
                acc[2][g] = __builtin_amdgcn_mfma_f32_16x16x32_bf16(af2, bv, acc[2][g], 0, 0, 0);
            }
        }

        // (d1) GRU elementwise from accumulators; G read direct (C-frag: col=l15, row=q*4+r)
        {
            const int pt = tags_s[t - 1];
            const int j = w * 16 + l15;
            const float br_ = bhh[j], bz_ = bhh[256 + j], bn_ = bhh[512 + j];
            #pragma unroll
            for (int mt = 0; mt < 3; ++mt) {
                #pragma unroll
                for (int r = 0; r < 4; ++r) {
                    int row = mt * 16 + q * 4 + r;
                    if (row > 32) continue;
                    int e = (row < 32) ? btag[row] : pt;
                    const float* gp = G + e * G3 + j;
                    float gir = gp[0], giz = gp[256], gin = gp[512];
                    float rr = sigm(gir + acc[mt][0][r] + br_);
                    float zz = sigm(giz + acc[mt][1][r] + bz_);
                    float nn = tanhr(gin + rr * (acc[mt][2][r] + bn_));
                    int src = (row < 32) ? par[row] : 32;
                    float hold = hn[cur][src * 260 + j];
                    hn[nxt][row * 260 + j] = (1.f - zz) * nn + zz * hold;
                }
            }
        }
        __syncthreads();

        // (d2) hb <- hnew (unpermuted) for the tr matmul
        for (int idx = tid; idx < 33 * 64; idx += 1024) {
            int k = idx >> 6, jq = (idx & 63) * 4;
            const float* hp = &hn[nxt][k * 260 + jq];
            __bf16* dp = &hb[k * 264 + jq];
            dp[0] = (__bf16)hp[0]; dp[1] = (__bf16)hp[1];
            dp[2] = (__bf16)hp[2]; dp[3] = (__bf16)hp[3];
        }
        __syncthreads();

        // (e) tr = hnew @ W_lin.T + b_lin  (waves 0..5: mt = w>>1, coltile = w&1)
        if (w < 6) {
            const int mt = w >> 1, ntc = w & 1;
            f32x4 a2 = {0.f, 0.f, 0.f, 0.f};
            #pragma unroll
            for (int kt = 0; kt < 8; ++kt) {
                const int kk = kt * 32 + q * 8;
                bf16x8 af = *(const bf16x8*)&hb[(mt * 16 + l15) * 264 + kk];
                bf16x8 bv = *(const bf16x8*)&wlin[((ntc * 8 + kt) * 64 + lane) * 8];
                a2 = __builtin_amdgcn_mfma_f32_16x16x32_bf16(af, bv, a2, 0, 0, 0);
            }
            #pragma unroll
            for (int r = 0; r < 4; ++r) {
                int row = mt * 16 + q * 4 + r;
                if (row <= 32) trs[row * 33 + ntc * 16 + l15] = a2[r] + blin_s[ntc * 16 + l15];
            }
        }
        __syncthreads();

        // (f) path score (faithful: em0 gathered every step) + (h) per-row rank sort
        const float m_t = mask_s[t];
        if (tid == 0) {
            int ct = tags_s[t];
            s_ps += (trs[32 * 33 + ct] + em_s[ct]) * m_t;
        }
        {
            const int k = tid >> 5, l32 = tid & 31;
            float bse = scores[btag[k]];          // faithful quirk: gather by prev TAG id
            float v = bse + (trs[k * 33 + l32] + em_s[t * 32 + l32]) * m_t;
            int cnt = 0;
            for (int jj = 0; jj < 32; ++jj) {
                float vj = __shfl(v, jj, 32);
                cnt += (vj > v) || (vj == v && jj < l32);
            }
            srtv[k * 33 + cnt] = v;
            srti[k * 33 + cnt] = (unsigned short)(k * 32 + l32);
        }
        __syncthreads();

        // (i) 32-way merge of sorted rows -> exact lax.top_k order
        if (tid < 32) {
            int r = tid, p = 0;
            float hv = srtv[r * 33];
            for (int i = 0; i < 32; ++i) {
                float bv = hv; int brr = r;
                #pragma unroll
                for (int off = 16; off >= 1; off >>= 1) {
                    float ov = __shfl_xor(bv, off, 32);
                    int orr = __shfl_xor(brr, off, 32);
                    if (ov > bv || (ov == bv && orr < brr)) { bv = ov; brr = orr; }
                }
                if (r == brr) {
                    scores[i] = bv;
                    int sidx = srti[r * 33 + p];
                    btag[i] = sidx & 31;
                    par[i] = sidx >> 5;
                    ++p;
                    hv = (p < 32) ? srtv[r * 33 + p] : -3.4e38f;
                }
            }
        }
        __syncthreads();
    }

    // ---- epilogue: logsumexp over sorted scores; accumulate (ps - logz) ----
    if (tid < 32) {
        float mx = scores[0];
        float ex = __expf(scores[tid] - mx);
        #pragma unroll
        for (int off = 16; off >= 1; off >>= 1) ex += __shfl_xor(ex, off, 32);
        if (tid == 0) {
            float logz = mx + logf(ex);
            atomicAdd(out, s_ps - logz);
        }
    }
}

extern "C" void kernel_launch(void* const* d_in, const int* in_sizes, int n_in,
                              void* d_out, int out_size, void* d_ws, size_t ws_size,
                              hipStream_t stream) {
    const float* emissions = (const float*)d_in[0];
    const int*   tags      = (const int*)d_in[1];
    const float* mask      = (const float*)d_in[2];
    const float* embedding = (const float*)d_in[3];
    const float* W_ih      = (const float*)d_in[4];
    const float* W_hh      = (const float*)d_in[5];
    const float* b_ih      = (const float*)d_in[6];
    const float* b_hh      = (const float*)d_in[7];
    const float* W_lin     = (const float*)d_in[8];
    const float* b_lin     = (const float*)d_in[9];
    float* out = (float*)d_out;

    char* ws = (char*)d_ws;
    float*  G     = (float*)ws;              // 33*768*4   = 101376 B
    float*  h1    = (float*)(ws + 101376);   // 256*4
    float*  tr0   = (float*)(ws + 102400);   // 32*4
    __bf16* Wpk   = (__bf16*)(ws + 102528);  // 24576*8*2  = 393216 B (frag-packed W_hh)
    __bf16* Wlpk  = (__bf16*)(ws + 495744);  // 1024*8*2   = 16384 B  (frag-packed W_lin)

    hipMemsetAsync(d_out, 0, sizeof(float) * out_size, stream);
    k_pre<<<133, 256, 0, stream>>>(embedding, W_ih, b_ih, W_hh, W_lin, G, Wpk, Wlpk);
    k_init<<<1, 256, 0, stream>>>(G, b_hh, W_lin, b_lin, h1, tr0);
    k_main<<<BAT, 1024, 0, stream>>>(emissions, tags, mask, G, h1, tr0,
                                     Wpk, Wlpk, b_hh, b_lin, out);
}

// Round 3
// 1311.805 us; speedup vs baseline: 2.8987x; 1.6921x over previous
//
#include <hip/hip_runtime.h>

#define SEQ 64
#define BAT 256
#define NT 32
#define EMB 256
#define HID 256
#define G3 768   // 3*HID

typedef __bf16 bf16x8 __attribute__((ext_vector_type(8)));
typedef float f32x4 __attribute__((ext_vector_type(4)));

__device__ __forceinline__ float sigm(float x) {
    x = fminf(fmaxf(x, -30.f), 30.f);
    return 1.f / (1.f + __expf(-x));
}
__device__ __forceinline__ float tanhr(float x) {
    x = fminf(fmaxf(x, -15.f), 15.f);
    float e = __expf(2.f * x);
    return (e - 1.f) / (e + 1.f);
}

// ---------------- K1: G = emb @ W_ih.T + b_ih ; pack W_hh/W_lin into MFMA-frag order ----
__global__ void k_pre(const float* __restrict__ emb, const float* __restrict__ W_ih,
                      const float* __restrict__ b_ih, const float* __restrict__ W_hh,
                      const float* __restrict__ W_lin,
                      float* __restrict__ G, __bf16* __restrict__ Wpk, __bf16* __restrict__ Wlpk)
{
    const int tid = threadIdx.x;
    const int blk = blockIdx.x;
    if (blk < 33) {
        __shared__ float es[EMB];
        es[tid] = emb[blk * EMB + tid];
        __syncthreads();
        const float4* e4 = (const float4*)es;
        #pragma unroll
        for (int g = 0; g < 3; ++g) {
            int c = g * HID + tid;
            const float4* w4 = (const float4*)(W_ih + c * EMB);
            float acc = b_ih[c];
            #pragma unroll 8
            for (int i = 0; i < EMB / 4; ++i) {
                float4 a = e4[i], w = w4[i];
                acc += a.x * w.x + a.y * w.y + a.z * w.z + a.w * w.w;
            }
            G[blk * G3 + c] = acc;
        }
    } else {
        int idx = (blk - 33) * 256 + tid;   // [0, 25600)
        if (idx < 24576) {                  // W_hh: 48 col-tiles * 8 kt * 64 lanes
            int c    = idx >> 9;
            int rem  = idx & 511;
            int kt   = rem >> 6;
            int lane = rem & 63;
            int row  = c * 16 + (lane & 15);
            int col  = kt * 32 + (lane >> 4) * 8;
            const float* src = W_hh + row * 256 + col;
            bf16x8 v;
            #pragma unroll
            for (int j = 0; j < 8; ++j) v[j] = (__bf16)src[j];
            *(bf16x8*)(Wpk + idx * 8) = v;
        } else {                            // W_lin: 2 col-tiles * 8 kt * 64 lanes
            int i2   = idx - 24576;
            int nt   = i2 >> 9;
            int rem  = i2 & 511;
            int kt   = rem >> 6;
            int lane = rem & 63;
            int row  = nt * 16 + (lane & 15);
            int col  = kt * 32 + (lane >> 4) * 8;
            const float* src = W_lin + row * 256 + col;
            bf16x8 v;
            #pragma unroll
            for (int j = 0; j < 8; ++j) v[j] = (__bf16)src[j];
            *(bf16x8*)(Wlpk + i2 * 8) = v;
        }
    }
}

// ---------------- K2: h1 = gru(emb[32], 0), trans0 = h1 @ W_lin.T + b_lin (exact fp32) ----
__global__ void k_init(const float* __restrict__ G, const float* __restrict__ b_hh,
                       const float* __restrict__ W_lin, const float* __restrict__ b_lin,
                       float* __restrict__ h1, float* __restrict__ tr0)
{
    __shared__ float hs[HID];
    int j = threadIdx.x;
    float gr = G[32 * G3 + j], gz = G[32 * G3 + HID + j], gn = G[32 * G3 + 2 * HID + j];
    float r = sigm(gr + b_hh[j]);
    float z = sigm(gz + b_hh[HID + j]);
    float n = tanhr(gn + r * b_hh[2 * HID + j]);
    float h = (1.f - z) * n;   // h0 = 0
    h1[j] = h; hs[j] = h;
    __syncthreads();
    if (j < NT) {
        const float4* w4 = (const float4*)(W_lin + j * HID);
        const float4* h4 = (const float4*)hs;
        float acc = b_lin[j];
        #pragma unroll 8
        for (int i = 0; i < HID / 4; ++i) {
            float4 a = h4[i], w = w4[i];
            acc += a.x * w.x + a.y * w.y + a.z * w.z + a.w * w.w;
        }
        tr0[j] = acc;
    }
}

// ---------------- K3: one 1024-thread workgroup (16 waves) per batch element ----------
// LDS-resident G (bf16), single fp32 state buffer, batched W-frag loads,
// parallel bitonic tree-merge for exact lax.top_k.
__global__ __launch_bounds__(1024, 4) void k_main(
    const float* __restrict__ em, const int* __restrict__ tags, const float* __restrict__ mask,
    const float* __restrict__ G, const float* __restrict__ h1w, const float* __restrict__ tr0w,
    const __bf16* __restrict__ Wpk, const __bf16* __restrict__ Wlpk,
    const float* __restrict__ bhhg, const float* __restrict__ bling,
    float* __restrict__ out)
{
    __shared__ float hn[33 * 260];                               // fp32 state (row 32 = path)
    __shared__ __attribute__((aligned(16))) __bf16 hb[48 * 264]; // bf16 A-matrix (rows 33..47 zero)
    __shared__ __attribute__((aligned(16))) __bf16 gl[33 * 784]; // bf16 G, all 33 embeddings
    __shared__ __attribute__((aligned(16))) __bf16 wlin[8192];   // packed W_lin frags
    __shared__ float trs[33 * 33];
    __shared__ float srtv[32 * 33];
    __shared__ unsigned short srti[32 * 33];
    __shared__ float bhh[768];
    __shared__ float em_s[SEQ * NT];
    __shared__ float mask_s[SEQ];
    __shared__ int tags_s[SEQ];
    __shared__ float scores[NT], blin_s[NT];
    __shared__ int btag[NT], par[NT];
    __shared__ float s_ps;

    const int tid = threadIdx.x;
    const int b = blockIdx.x;
    const int w = tid >> 6;
    const int lane = tid & 63;
    const int q = lane >> 4;
    const int l15 = lane & 15;

    // ---- prologue staging ----
    if (tid < 768) bhh[tid] = bhhg[tid];
    else if (tid < 832) mask_s[tid - 768] = mask[(tid - 768) * BAT + b];
    else if (tid < 896) tags_s[tid - 832] = tags[(tid - 832) * BAT + b];
    else if (tid < 928) { int i = tid - 896; blin_s[i] = bling[i]; par[i] = i; }
    ((bf16x8*)wlin)[tid] = ((const bf16x8*)Wlpk)[tid];
    for (int idx = tid; idx < SEQ * NT; idx += 1024)
        em_s[idx] = em[((idx >> 5) * BAT + b) * NT + (idx & 31)];
    for (int idx = tid; idx < 33 * 256; idx += 1024)
        hn[(idx >> 8) * 260 + (idx & 255)] = h1w[idx & 255];
    for (int idx = tid; idx < 33 * 768; idx += 1024) {
        int row = idx / 768, col = idx - row * 768;
        gl[row * 784 + col] = (__bf16)G[idx];
    }
    for (int idx = tid; idx < 15 * 264; idx += 1024)
        hb[33 * 264 + idx] = (__bf16)0.f;
    __syncthreads();

    // ---- initial top_k of s_init = (trans0 + em0) * mask0 (rank sort, ties -> lower idx) ----
    if (tid < 32) {
        float m0 = mask_s[0];
        float v = (tr0w[tid] + em_s[tid]) * m0;
        int cnt = 0;
        for (int jj = 0; jj < 32; ++jj) {
            float vj = __shfl(v, jj, 32);
            cnt += (vj > v) || (vj == v && jj < tid);
        }
        scores[cnt] = v; btag[cnt] = tid;
    }
    if (tid == 64) {
        int t0 = tags_s[0];
        s_ps = (tr0w[t0] + em_s[t0]) * mask_s[0];
    }
    __syncthreads();

    for (int t = 1; t < SEQ; ++t) {
        // (b) hb <- parent-permuted bf16 state (reads all of hn, then barrier)
        for (int idx = tid; idx < 33 * 64; idx += 1024) {
            int k = idx >> 6, jq = (idx & 63) * 4;
            int src = (k < 32) ? par[k] : 32;
            const float* hp = &hn[src * 260 + jq];
            __bf16* dp = &hb[k * 264 + jq];
            dp[0] = (__bf16)hp[0]; dp[1] = (__bf16)hp[1];
            dp[2] = (__bf16)hp[2]; dp[3] = (__bf16)hp[3];
        }
        __syncthreads();

        // (c) gh = hidden @ W_hh.T ; W-frags loaded in two 12-wide batches for MLP
        f32x4 acc[3][3];
        #pragma unroll
        for (int mt = 0; mt < 3; ++mt)
            #pragma unroll
            for (int g = 0; g < 3; ++g) {
                f32x4 z = {0.f, 0.f, 0.f, 0.f};
                acc[mt][g] = z;
            }
        const __bf16* wbase = Wpk + w * 4096 + lane * 8;
        #pragma unroll
        for (int h2 = 0; h2 < 2; ++h2) {
            bf16x8 bf[12];
            #pragma unroll
            for (int kt2 = 0; kt2 < 4; ++kt2)
                #pragma unroll
                for (int g = 0; g < 3; ++g)
                    bf[kt2 * 3 + g] = *(const bf16x8*)(wbase + g * 65536 + (h2 * 4 + kt2) * 512);
            #pragma unroll
            for (int kt2 = 0; kt2 < 4; ++kt2) {
                const int kk = (h2 * 4 + kt2) * 32 + q * 8;
                bf16x8 af0 = *(const bf16x8*)&hb[l15 * 264 + kk];
                bf16x8 af1 = *(const bf16x8*)&hb[(16 + l15) * 264 + kk];
                bf16x8 af2 = *(const bf16x8*)&hb[(32 + l15) * 264 + kk];
                #pragma unroll
                for (int g = 0; g < 3; ++g) {
                    acc[0][g] = __builtin_amdgcn_mfma_f32_16x16x32_bf16(af0, bf[kt2 * 3 + g], acc[0][g], 0, 0, 0);
                    acc[1][g] = __builtin_amdgcn_mfma_f32_16x16x32_bf16(af1, bf[kt2 * 3 + g], acc[1][g], 0, 0, 0);
                    acc[2][g] = __builtin_amdgcn_mfma_f32_16x16x32_bf16(af2, bf[kt2 * 3 + g], acc[2][g], 0, 0, 0);
                }
            }
        }

        // (d1) GRU elementwise; gi from LDS-resident bf16 G; hold from bf16 hb
        {
            const int pt = tags_s[t - 1];
            const int j = w * 16 + l15;
            const float br_ = bhh[j], bz_ = bhh[256 + j], bn_ = bhh[512 + j];
            #pragma unroll
            for (int mt = 0; mt < 3; ++mt) {
                #pragma unroll
                for (int r = 0; r < 4; ++r) {
                    int row = mt * 16 + q * 4 + r;
                    if (row > 32) continue;
                    int e = (row < 32) ? btag[row] : pt;
                    const __bf16* gp = &gl[e * 784 + j];
                    float gir = (float)gp[0], giz = (float)gp[256], gin = (float)gp[512];
                    float rr = sigm(gir + acc[mt][0][r] + br_);
                    float zz = sigm(giz + acc[mt][1][r] + bz_);
                    float nn = tanhr(gin + rr * (acc[mt][2][r] + bn_));
                    float hold = (float)hb[row * 264 + j];
                    hn[row * 260 + j] = (1.f - zz) * nn + zz * hold;
                }
            }
        }
        __syncthreads();

        // (d2) hb <- hnew (unpermuted) for the tr matmul
        for (int idx = tid; idx < 33 * 64; idx += 1024) {
            int k = idx >> 6, jq = (idx & 63) * 4;
            const float* hp = &hn[k * 260 + jq];
            __bf16* dp = &hb[k * 264 + jq];
            dp[0] = (__bf16)hp[0]; dp[1] = (__bf16)hp[1];
            dp[2] = (__bf16)hp[2]; dp[3] = (__bf16)hp[3];
        }
        __syncthreads();

        // (e) tr = hnew @ W_lin.T + b_lin  (waves 0..5: mt = w>>1, coltile = w&1)
        if (w < 6) {
            const int mt = w >> 1, ntc = w & 1;
            f32x4 a2 = {0.f, 0.f, 0.f, 0.f};
            #pragma unroll
            for (int kt = 0; kt < 8; ++kt) {
                const int kk = kt * 32 + q * 8;
                bf16x8 af = *(const bf16x8*)&hb[(mt * 16 + l15) * 264 + kk];
                bf16x8 bv = *(const bf16x8*)&wlin[((ntc * 8 + kt) * 64 + lane) * 8];
                a2 = __builtin_amdgcn_mfma_f32_16x16x32_bf16(af, bv, a2, 0, 0, 0);
            }
            #pragma unroll
            for (int r = 0; r < 4; ++r) {
                int row = mt * 16 + q * 4 + r;
                if (row <= 32) trs[row * 33 + ntc * 16 + l15] = a2[r] + blin_s[ntc * 16 + l15];
            }
        }
        __syncthreads();

        // (f) path score + (h) per-beam-row rank sort of candidates
        const float m_t = mask_s[t];
        if (tid == 0) {
            int ct = tags_s[t];
            s_ps += (trs[32 * 33 + ct] + em_s[ct]) * m_t;
        }
        {
            const int k = tid >> 5, l32 = tid & 31;
            float bse = scores[btag[k]];          // faithful quirk: gather by prev TAG id
            float v = bse + (trs[k * 33 + l32] + em_s[t * 32 + l32]) * m_t;
            int cnt = 0;
            for (int jj = 0; jj < 32; ++jj) {
                float vj = __shfl(v, jj, 32);
                cnt += (vj > v) || (vj == v && jj < l32);
            }
            srtv[k * 33 + cnt] = v;
            srti[k * 33 + cnt] = (unsigned short)(k * 32 + l32);
        }
        __syncthreads();

        // (i) bitonic tree-merge of 32 sorted rows -> exact lax.top_k order.
        // Comparator: (v desc, flat idx asc) — a strict total order, so
        // m[i]=max(A[i],B[31-i]) keeps exactly the top-32 and is bitonic.
        {
            const int gidx = tid >> 5, l32 = tid & 31;
            #pragma unroll
            for (int st = 1; st < 32; st <<= 1) {
                const int ngroups = 16 / st;
                if (gidx < ngroups) {
                    const int r = gidx * 2 * st;
                    float av = srtv[r * 33 + l32];
                    int   ai = srti[r * 33 + l32];
                    float bv = srtv[(r + st) * 33 + (31 - l32)];
                    int   bi = srti[(r + st) * 33 + (31 - l32)];
                    float mv; int mi;
                    if (av > bv || (av == bv && ai < bi)) { mv = av; mi = ai; }
                    else                                   { mv = bv; mi = bi; }
                    #pragma unroll
                    for (int off = 16; off >= 1; off >>= 1) {
                        float ov = __shfl_xor(mv, off, 32);
                        int   oi = __shfl_xor(mi, off, 32);
                        bool up = (l32 & off) == 0;
                        bool omax = (ov > mv) || (ov == mv && oi < mi);
                        if (up == omax) { mv = ov; mi = oi; }
                    }
                    if (st == 16) {
                        scores[l32] = mv; btag[l32] = mi & 31; par[l32] = mi >> 5;
                    } else {
                        srtv[r * 33 + l32] = mv; srti[r * 33 + l32] = (unsigned short)mi;
                    }
                }
                __syncthreads();
            }
        }
    }

    // ---- epilogue: logsumexp over sorted scores; accumulate (ps - logz) ----
    if (tid < 32) {
        float mx = scores[0];
        float ex = __expf(scores[tid] - mx);
        #pragma unroll
        for (int off = 16; off >= 1; off >>= 1) ex += __shfl_xor(ex, off, 32);
        if (tid == 0) {
            float logz = mx + logf(ex);
            atomicAdd(out, s_ps - logz);
        }
    }
}

extern "C" void kernel_launch(void* const* d_in, const int* in_sizes, int n_in,
                              void* d_out, int out_size, void* d_ws, size_t ws_size,
                              hipStream_t stream) {
    const float* emissions = (const float*)d_in[0];
    const int*   tags      = (const int*)d_in[1];
    const float* mask      = (const float*)d_in[2];
    const float* embedding = (const float*)d_in[3];
    const float* W_ih      = (const float*)d_in[4];
    const float* W_hh      = (const float*)d_in[5];
    const float* b_ih      = (const float*)d_in[6];
    const float* b_hh      = (const float*)d_in[7];
    const float* W_lin     = (const float*)d_in[8];
    const float* b_lin     = (const float*)d_in[9];
    float* out = (float*)d_out;

    char* ws = (char*)d_ws;
    float*  G     = (float*)ws;              // 33*768*4   = 101376 B
    float*  h1    = (float*)(ws + 101376);   // 256*4
    float*  tr0   = (float*)(ws + 102400);   // 32*4
    __bf16* Wpk   = (__bf16*)(ws + 102528);  // 24576*8*2  = 393216 B (frag-packed W_hh)
    __bf16* Wlpk  = (__bf16*)(ws + 495744);  // 1024*8*2   = 16384 B  (frag-packed W_lin)

    hipMemsetAsync(d_out, 0, sizeof(float) * out_size, stream);
    k_pre<<<133, 256, 0, stream>>>(embedding, W_ih, b_ih, W_hh, W_lin, G, Wpk, Wlpk);
    k_init<<<1, 256, 0, stream>>>(G, b_hh, W_lin, b_lin, h1, tr0);
    k_main<<<BAT, 1024, 0, stream>>>(emissions, tags, mask, G, h1, tr0,
                                     Wpk, Wlpk, b_hh, b_lin, out);
}

// Round 4
// 817.224 us; speedup vs baseline: 4.6531x; 1.6052x over previous
//
#include <hip/hip_runtime.h>

#define SEQ 64
#define BAT 256
#define NT 32
#define EMB 256
#define HID 256
#define G3 768   // 3*HID

typedef __bf16 bf16x8 __attribute__((ext_vector_type(8)));
typedef float f32x4 __attribute__((ext_vector_type(4)));

__device__ __forceinline__ float sigm(float x) {
    x = fminf(fmaxf(x, -30.f), 30.f);
    return 1.f / (1.f + __expf(-x));
}
__device__ __forceinline__ float tanhr(float x) {
    x = fminf(fmaxf(x, -15.f), 15.f);
    float e = __expf(2.f * x);
    return (e - 1.f) / (e + 1.f);
}

// ---- K1: G = emb @ W_ih.T + b_ih ; W_hh -> fp8 frag-pack ; W_lin -> bf16 frag-pack ----
// Frag chunk ((coltile*8 + kt)*64 + lane) holds W[coltile*16 + (lane&15)][kt*32 + (lane>>4)*8 + 0..7].
__global__ void k_pre(const float* __restrict__ emb, const float* __restrict__ W_ih,
                      const float* __restrict__ b_ih, const float* __restrict__ W_hh,
                      const float* __restrict__ W_lin,
                      float* __restrict__ G, int2* __restrict__ Wpk8, __bf16* __restrict__ Wlpk)
{
    const int tid = threadIdx.x;
    const int blk = blockIdx.x;
    if (blk < 33) {
        __shared__ float es[EMB];
        es[tid] = emb[blk * EMB + tid];
        __syncthreads();
        const float4* e4 = (const float4*)es;
        #pragma unroll
        for (int g = 0; g < 3; ++g) {
            int c = g * HID + tid;
            const float4* w4 = (const float4*)(W_ih + c * EMB);
            float acc = b_ih[c];
            #pragma unroll 8
            for (int i = 0; i < EMB / 4; ++i) {
                float4 a = e4[i], w = w4[i];
                acc += a.x * w.x + a.y * w.y + a.z * w.z + a.w * w.w;
            }
            G[blk * G3 + c] = acc;
        }
    } else if (blk < 129) {                 // W_hh fp8 pack: 24576 chunks
        int idx  = (blk - 33) * 256 + tid;
        int c    = idx >> 9;
        int rem  = idx & 511;
        int kt   = rem >> 6;
        int lane = rem & 63;
        int row  = c * 16 + (lane & 15);
        int col  = kt * 32 + (lane >> 4) * 8;
        const float* src = W_hh + row * 256 + col;
        int lo = __builtin_amdgcn_cvt_pk_fp8_f32(src[0], src[1], 0, 0);
        lo     = __builtin_amdgcn_cvt_pk_fp8_f32(src[2], src[3], lo, 1);
        int hi = __builtin_amdgcn_cvt_pk_fp8_f32(src[4], src[5], 0, 0);
        hi     = __builtin_amdgcn_cvt_pk_fp8_f32(src[6], src[7], hi, 1);
        Wpk8[idx] = make_int2(lo, hi);
    } else {                                // W_lin bf16 pack: 1024 chunks
        int i2   = (blk - 129) * 256 + tid;
        int nt   = i2 >> 9;
        int rem  = i2 & 511;
        int kt   = rem >> 6;
        int lane = rem & 63;
        int row  = nt * 16 + (lane & 15);
        int col  = kt * 32 + (lane >> 4) * 8;
        const float* src = W_lin + row * 256 + col;
        bf16x8 v;
        #pragma unroll
        for (int j = 0; j < 8; ++j) v[j] = (__bf16)src[j];
        *(bf16x8*)(Wlpk + i2 * 8) = v;
    }
}

// ---- K2: h1 = gru(emb[32], 0), trans0 = h1 @ W_lin.T + b_lin (exact fp32) ----
__global__ void k_init(const float* __restrict__ G, const float* __restrict__ b_hh,
                       const float* __restrict__ W_lin, const float* __restrict__ b_lin,
                       float* __restrict__ h1, float* __restrict__ tr0)
{
    __shared__ float hs[HID];
    int j = threadIdx.x;
    float gr = G[32 * G3 + j], gz = G[32 * G3 + HID + j], gn = G[32 * G3 + 2 * HID + j];
    float r = sigm(gr + b_hh[j]);
    float z = sigm(gz + b_hh[HID + j]);
    float n = tanhr(gn + r * b_hh[2 * HID + j]);
    float h = (1.f - z) * n;   // h0 = 0
    h1[j] = h; hs[j] = h;
    __syncthreads();
    if (j < NT) {
        const float4* w4 = (const float4*)(W_lin + j * HID);
        const float4* h4 = (const float4*)hs;
        float acc = b_lin[j];
        #pragma unroll 8
        for (int i = 0; i < HID / 4; ++i) {
            float4 a = h4[i], w = w4[i];
            acc += a.x * w.x + a.y * w.y + a.z * w.z + a.w * w.w;
        }
        tr0[j] = acc;
    }
}

// ---- K3: one 1024-thread workgroup per batch element; W_hh fp8 frags register-stationary ----
__global__ __launch_bounds__(1024, 4) void k_main(
    const float* __restrict__ em, const int* __restrict__ tags, const float* __restrict__ mask,
    const float* __restrict__ G, const float* __restrict__ h1w, const float* __restrict__ tr0w,
    const long* __restrict__ Wpk8, const __bf16* __restrict__ Wlpk,
    const float* __restrict__ bhhg, const float* __restrict__ bling,
    float* __restrict__ out)
{
    __shared__ __attribute__((aligned(16))) __bf16 gl[33 * 784];      // bf16 G (all 33 embeddings)
    __shared__ __attribute__((aligned(16))) __bf16 hb[2][48 * 264];   // bf16 h state ping-pong (rows 33..47 zero)
    __shared__ __attribute__((aligned(16))) unsigned char hq[48 * 272]; // fp8 permuted A for gh matmul
    __shared__ __attribute__((aligned(16))) __bf16 wlin[8192];        // packed W_lin frags
    __shared__ float trs[33 * 33];
    __shared__ float srtv[32 * 33];
    __shared__ unsigned short srti[32 * 33];
    __shared__ float bhh[768];
    __shared__ float em_s[SEQ * NT];
    __shared__ float mask_s[SEQ];
    __shared__ int tags_s[SEQ];
    __shared__ float scores[NT], blin_s[NT];
    __shared__ int btag[NT], par[NT];
    __shared__ float s_ps;

    const int tid = threadIdx.x;
    const int b = blockIdx.x;
    const int w = tid >> 6;
    const int lane = tid & 63;
    const int q = lane >> 4;
    const int l15 = lane & 15;

    // ---- W_hh fp8 fragments -> registers, stationary for the whole sequence ----
    long wreg[24];
    #pragma unroll
    for (int g = 0; g < 3; ++g)
        #pragma unroll
        for (int kt = 0; kt < 8; ++kt)
            wreg[g * 8 + kt] = Wpk8[((g * 16 + w) * 8 + kt) * 64 + lane];

    // ---- prologue staging ----
    if (tid < 768) bhh[tid] = bhhg[tid];
    else if (tid < 832) mask_s[tid - 768] = mask[(tid - 768) * BAT + b];
    else if (tid < 896) tags_s[tid - 832] = tags[(tid - 832) * BAT + b];
    else if (tid < 928) { int i = tid - 896; blin_s[i] = bling[i]; par[i] = i; }
    ((bf16x8*)wlin)[tid] = ((const bf16x8*)Wlpk)[tid];
    for (int idx = tid; idx < SEQ * NT; idx += 1024)
        em_s[idx] = em[((idx >> 5) * BAT + b) * NT + (idx & 31)];
    for (int idx = tid; idx < 33 * 768; idx += 1024) {
        int row = idx / 768, col = idx - row * 768;
        gl[row * 784 + col] = (__bf16)G[idx];
    }
    for (int idx = tid; idx < 33 * 256; idx += 1024)
        hb[0][(idx >> 8) * 264 + (idx & 255)] = (__bf16)h1w[idx & 255];
    for (int idx = tid; idx < 15 * 264; idx += 1024) {      // zero pad rows 33..47
        hb[0][33 * 264 + idx] = (__bf16)0.f;
        hb[1][33 * 264 + idx] = (__bf16)0.f;
    }
    for (int idx = tid; idx < 15 * 272; idx += 1024)
        hq[33 * 272 + idx] = 0;
    __syncthreads();

    // ---- initial top_k of s_init = (trans0 + em0) * mask0 (rank sort, ties -> lower idx) ----
    if (tid < 32) {
        float m0 = mask_s[0];
        float v = (tr0w[tid] + em_s[tid]) * m0;
        int cnt = 0;
        for (int jj = 0; jj < 32; ++jj) {
            float vj = __shfl(v, jj, 32);
            cnt += (vj > v) || (vj == v && jj < tid);
        }
        scores[cnt] = v; btag[cnt] = tid;
    }
    if (tid == 64) {
        int t0 = tags_s[0];
        s_ps = (tr0w[t0] + em_s[t0]) * mask_s[0];
    }
    __syncthreads();

    for (int t = 1; t < SEQ; ++t) {
        const int cur = (t - 1) & 1, nxt = t & 1;

        // (b) hq <- fp8(parent-permuted h) ; 1056 8-elem chunks
        for (int c = tid; c < 33 * 32; c += 1024) {
            int row = c >> 5, off = (c & 31) * 8;
            int src = (row < 32) ? par[row] : 32;
            bf16x8 hv = *(const bf16x8*)&hb[cur][src * 264 + off];
            int lo = __builtin_amdgcn_cvt_pk_fp8_f32((float)hv[0], (float)hv[1], 0, 0);
            lo     = __builtin_amdgcn_cvt_pk_fp8_f32((float)hv[2], (float)hv[3], lo, 1);
            int hi = __builtin_amdgcn_cvt_pk_fp8_f32((float)hv[4], (float)hv[5], 0, 0);
            hi     = __builtin_amdgcn_cvt_pk_fp8_f32((float)hv[6], (float)hv[7], hi, 1);
            *(int2*)&hq[row * 272 + off] = make_int2(lo, hi);
        }
        __syncthreads();

        // (c) gh = hidden @ W_hh.T  (fp8 x fp8, W from registers — zero global traffic)
        f32x4 acc[3][3];
        #pragma unroll
        for (int mt = 0; mt < 3; ++mt)
            #pragma unroll
            for (int g = 0; g < 3; ++g) {
                f32x4 z = {0.f, 0.f, 0.f, 0.f};
                acc[mt][g] = z;
            }
        #pragma unroll
        for (int kt = 0; kt < 8; ++kt) {
            const int kb = kt * 32 + q * 8;
            long af0 = *(const long*)&hq[l15 * 272 + kb];
            long af1 = *(const long*)&hq[(16 + l15) * 272 + kb];
            long af2 = *(const long*)&hq[(32 + l15) * 272 + kb];
            #pragma unroll
            for (int g = 0; g < 3; ++g) {
                acc[0][g] = __builtin_amdgcn_mfma_f32_16x16x32_fp8_fp8(af0, wreg[g * 8 + kt], acc[0][g], 0, 0, 0);
                acc[1][g] = __builtin_amdgcn_mfma_f32_16x16x32_fp8_fp8(af1, wreg[g * 8 + kt], acc[1][g], 0, 0, 0);
                acc[2][g] = __builtin_amdgcn_mfma_f32_16x16x32_fp8_fp8(af2, wreg[g * 8 + kt], acc[2][g], 0, 0, 0);
            }
        }

        // (d1) GRU elementwise; gi from LDS bf16 G; hold from bf16 hb[cur]; write hb[nxt]
        {
            const int pt = tags_s[t - 1];
            const int j = w * 16 + l15;
            const float br_ = bhh[j], bz_ = bhh[256 + j], bn_ = bhh[512 + j];
            #pragma unroll
            for (int mt = 0; mt < 3; ++mt) {
                #pragma unroll
                for (int r = 0; r < 4; ++r) {
                    int row = mt * 16 + q * 4 + r;
                    if (row > 32) continue;
                    int e = (row < 32) ? btag[row] : pt;
                    const __bf16* gp = &gl[e * 784 + j];
                    float gir = (float)gp[0], giz = (float)gp[256], gin = (float)gp[512];
                    float rr = sigm(gir + acc[mt][0][r] + br_);
                    float zz = sigm(giz + acc[mt][1][r] + bz_);
                    float nn = tanhr(gin + rr * (acc[mt][2][r] + bn_));
                    int src = (row < 32) ? par[row] : 32;
                    float hold = (float)hb[cur][src * 264 + j];
                    hb[nxt][row * 264 + j] = (__bf16)((1.f - zz) * nn + zz * hold);
                }
            }
        }
        __syncthreads();

        // (e) tr = hnew @ W_lin.T + b_lin  (bf16; waves 0..5: mt = w>>1, coltile = w&1)
        if (w < 6) {
            const int mt = w >> 1, ntc = w & 1;
            f32x4 a2 = {0.f, 0.f, 0.f, 0.f};
            #pragma unroll
            for (int kt = 0; kt < 8; ++kt) {
                const int kk = kt * 32 + q * 8;
                bf16x8 af = *(const bf16x8*)&hb[nxt][(mt * 16 + l15) * 264 + kk];
                bf16x8 bv = *(const bf16x8*)&wlin[((ntc * 8 + kt) * 64 + lane) * 8];
                a2 = __builtin_amdgcn_mfma_f32_16x16x32_bf16(af, bv, a2, 0, 0, 0);
            }
            #pragma unroll
            for (int r = 0; r < 4; ++r) {
                int row = mt * 16 + q * 4 + r;
                if (row <= 32) trs[row * 33 + ntc * 16 + l15] = a2[r] + blin_s[ntc * 16 + l15];
            }
        }
        __syncthreads();

        // (f) path score + (h) per-beam-row rank sort of candidates
        const float m_t = mask_s[t];
        if (tid == 0) {
            int ct = tags_s[t];
            s_ps += (trs[32 * 33 + ct] + em_s[ct]) * m_t;
        }
        {
            const int k = tid >> 5, l32 = tid & 31;
            float bse = scores[btag[k]];          // faithful quirk: gather by prev TAG id
            float v = bse + (trs[k * 33 + l32] + em_s[t * 32 + l32]) * m_t;
            int cnt = 0;
            for (int jj = 0; jj < 32; ++jj) {
                float vj = __shfl(v, jj, 32);
                cnt += (vj > v) || (vj == v && jj < l32);
            }
            srtv[k * 33 + cnt] = v;
            srti[k * 33 + cnt] = (unsigned short)(k * 32 + l32);
        }
        __syncthreads();

        // (i) bitonic tree-merge of 32 sorted rows -> exact lax.top_k order
        {
            const int gidx = tid >> 5, l32 = tid & 31;
            #pragma unroll
            for (int st = 1; st < 32; st <<= 1) {
                const int ngroups = 16 / st;
                if (gidx < ngroups) {
                    const int r = gidx * 2 * st;
                    float av = srtv[r * 33 + l32];
                    int   ai = srti[r * 33 + l32];
                    float bv = srtv[(r + st) * 33 + (31 - l32)];
                    int   bi = srti[(r + st) * 33 + (31 - l32)];
                    float mv; int mi;
                    if (av > bv || (av == bv && ai < bi)) { mv = av; mi = ai; }
                    else                                   { mv = bv; mi = bi; }
                    #pragma unroll
                    for (int off = 16; off >= 1; off >>= 1) {
                        float ov = __shfl_xor(mv, off, 32);
                        int   oi = __shfl_xor(mi, off, 32);
                        bool up = (l32 & off) == 0;
                        bool omax = (ov > mv) || (ov == mv && oi < mi);
                        if (up == omax) { mv = ov; mi = oi; }
                    }
                    if (st == 16) {
                        scores[l32] = mv; btag[l32] = mi & 31; par[l32] = mi >> 5;
                    } else {
                        srtv[r * 33 + l32] = mv; srti[r * 33 + l32] = (unsigned short)mi;
                    }
                }
                __syncthreads();
            }
        }
    }

    // ---- epilogue ----
    if (tid < 32) {
        float mx = scores[0];
        float ex = __expf(scores[tid] - mx);
        #pragma unroll
        for (int off = 16; off >= 1; off >>= 1) ex += __shfl_xor(ex, off, 32);
        if (tid == 0) {
            float logz = mx + logf(ex);
            atomicAdd(out, s_ps - logz);
        }
    }
}

extern "C" void kernel_launch(void* const* d_in, const int* in_sizes, int n_in,
                              void* d_out, int out_size, void* d_ws, size_t ws_size,
                              hipStream_t stream) {
    const float* emissions = (const float*)d_in[0];
    const int*   tags      = (const int*)d_in[1];
    const float* mask      = (const float*)d_in[2];
    const float* embedding = (const float*)d_in[3];
    const float* W_ih      = (const float*)d_in[4];
    const float* W_hh      = (const float*)d_in[5];
    const float* b_ih      = (const float*)d_in[6];
    const float* b_hh      = (const float*)d_in[7];
    const float* W_lin     = (const float*)d_in[8];
    const float* b_lin     = (const float*)d_in[9];
    float* out = (float*)d_out;

    char* ws = (char*)d_ws;
    float*  G     = (float*)ws;              // 33*768*4   = 101376 B
    float*  h1    = (float*)(ws + 101376);   // 256*4
    float*  tr0   = (float*)(ws + 102400);   // 32*4
    int2*   Wpk8  = (int2*)(ws + 102528);    // 24576*8    = 196608 B (fp8 frag-packed W_hh)
    __bf16* Wlpk  = (__bf16*)(ws + 299136);  // 1024*8*2   = 16384 B  (bf16 frag-packed W_lin)

    hipMemsetAsync(d_out, 0, sizeof(float) * out_size, stream);
    k_pre<<<133, 256, 0, stream>>>(embedding, W_ih, b_ih, W_hh, W_lin, G, Wpk8, Wlpk);
    k_init<<<1, 256, 0, stream>>>(G, b_hh, W_lin, b_lin, h1, tr0);
    k_main<<<BAT, 1024, 0, stream>>>(emissions, tags, mask, G, h1, tr0,
                                     (const long*)Wpk8, Wlpk, b_hh, b_lin, out);
}